// Round 7
// baseline (238.067 us; speedup 1.0000x reference)
//
#include <hip/hip_runtime.h>
#include <hip/hip_bf16.h>
#include <stdint.h>
#include <utility>

#define B_SZ 16384
#define P_SZ 8
#define D_SZ 512
#define A_SZ 64
#define K1 576    // D + A
#define H_SZ 1024
#define NSEG 64
#define MB_MAX 264              // max 64-row m-blocks after per-policy padding
#define BPAD (B_SZ + P_SZ*64)   // 16896 padded sorted-row capacity
#define PREP_BLOCKS (BPAD * 72 / 256)   // 4752
#define TRANS_BLOCKS (32 * 32 * 16)     // 16384

// s_waitcnt imm: vmcnt [3:0]+[15:14], expcnt [6:4], lgkmcnt [11:8]
#define WAIT_VM8  0x0F78  // vmcnt<=8
#define WAIT_VM0  0x0F70  // vmcnt==0

typedef __bf16 bf16_t;
typedef __bf16 bf16x8 __attribute__((ext_vector_type(8)));
typedef float f32x4 __attribute__((ext_vector_type(4)));

__device__ __forceinline__ void glds16(const void* g, void* l) {
    __builtin_amdgcn_global_load_lds(
        (const __attribute__((address_space(1))) unsigned*)g,
        (__attribute__((address_space(3))) unsigned*)l, 16, 0, 0);
}

template <int... Ks, typename F>
__device__ __forceinline__ void static_for_impl(std::integer_sequence<int, Ks...>, F&& f) {
    (f(std::integral_constant<int, Ks>{}), ...);
}
template <int N, typename F>
__device__ __forceinline__ void static_for(F&& f) {
    static_for_impl(std::make_integer_sequence<int, N>{}, (F&&)f);
}

// ---------------- sort prep ----------------

__global__ __launch_bounds__(256) void hist_block(const int* __restrict__ pol,
                                                  int* __restrict__ blockhist,
                                                  int* __restrict__ rowidx) {
    __shared__ int lc[P_SZ];
    int t = threadIdx.x;
    if (t < P_SZ) lc[t] = 0;
    __syncthreads();
    int gid = blockIdx.x * 256 + t;
    rowidx[gid] = -1;
    if (gid < BPAD - B_SZ) rowidx[B_SZ + gid] = -1;
    atomicAdd(&lc[pol[gid]], 1);
    __syncthreads();
    if (t < P_SZ) blockhist[blockIdx.x * P_SZ + t] = lc[t];
}

__global__ __launch_bounds__(64) void prefix_kernel(const int* __restrict__ blockhist,
                                                    int* __restrict__ counts,
                                                    int* __restrict__ cursors,
                                                    int* __restrict__ blk_p) {
    int t = threadIdx.x;
    if (t < P_SZ) {
        int s = 0;
        for (int b = 0; b < NSEG; ++b) s += blockhist[b * P_SZ + t];
        counts[t] = s;
    }
    __syncthreads();
    if (t == 0) {
        int run = 0;
        for (int p = 0; p < P_SZ; ++p) {
            cursors[p] = run;
            int nb = (counts[p] + 63) >> 6;
            for (int b = 0; b < nb; ++b) blk_p[(run >> 6) + b] = p;
            run += nb * 64;
        }
        for (int b = run >> 6; b < MB_MAX; ++b) blk_p[b] = -1;
    }
}

__global__ __launch_bounds__(256) void scatter_agg(const int* __restrict__ pol,
                                                   int* __restrict__ cursors,
                                                   int* __restrict__ rowidx) {
    __shared__ int lc[P_SZ], base_s[P_SZ];
    int t = threadIdx.x;
    if (t < P_SZ) lc[t] = 0;
    __syncthreads();
    int i = blockIdx.x * 256 + t;
    int p = pol[i];
    int lpos = atomicAdd(&lc[p], 1);
    __syncthreads();
    if (t < P_SZ) base_s[t] = atomicAdd(&cursors[t], lc[t]);
    __syncthreads();
    rowidx[base_s[p] + lpos] = i;
}

// ---------------- prep_all: fused x-gather/convert + weight transposes ----------------
// blocks [0, PREP_BLOCKS): xs[s] = bf16([latents|actions][rowidx[s]])
// blocks [PREP_BLOCKS, +TRANS_BLOCKS): W1/W2 [P][K][N] f32 -> [P][N][K] bf16

__global__ __launch_bounds__(256) void prep_all(const float* __restrict__ latents,
                                                const float* __restrict__ actions,
                                                const int* __restrict__ rowidx,
                                                const float* __restrict__ W1,
                                                const float* __restrict__ W2,
                                                bf16_t* __restrict__ xs,
                                                bf16_t* __restrict__ w1t,
                                                bf16_t* __restrict__ w2t) {
    int bx = blockIdx.x;
    int tid = threadIdx.x;
    if (bx < PREP_BLOCKS) {
        int idx = bx * 256 + tid;
        int s = idx / 72;
        int col = (idx - s * 72) * 8;
        int g = rowidx[s];
        bf16x8 o;
        if (g < 0) {
            o = (bf16x8){0,0,0,0,0,0,0,0};
        } else {
            const float* src;
            if (col < D_SZ) src = latents + (size_t)g * D_SZ + col;
            else            src = actions + (size_t)g * A_SZ + (col - D_SZ);
            f32x4 v0 = *(const f32x4*)src;
            f32x4 v1 = *(const f32x4*)(src + 4);
            o[0] = (bf16_t)v0[0]; o[1] = (bf16_t)v0[1]; o[2] = (bf16_t)v0[2]; o[3] = (bf16_t)v0[3];
            o[4] = (bf16_t)v1[0]; o[5] = (bf16_t)v1[1]; o[6] = (bf16_t)v1[2]; o[7] = (bf16_t)v1[3];
        }
        *(bf16x8*)(xs + (size_t)s * K1 + col) = o;
        return;
    }
    int tz = bx - PREP_BLOCKS;        // 0..16383
    int z = tz >> 10;                 // 0..15
    int rem = tz & 1023;
    int k0 = (rem & 31) * 32, n0 = (rem >> 5) * 32;
    int K = (z < P_SZ) ? K1 : H_SZ;
    int N = (z < P_SZ) ? H_SZ : D_SZ;
    if (k0 >= K || n0 >= N) return;
    int p = z & 7;
    const float* Wp = ((z < P_SZ) ? W1 : W2) + (size_t)p * K * N;
    bf16_t* WTp = ((z < P_SZ) ? w1t : w2t) + (size_t)p * N * K;
    __shared__ float ls[32][33];
#pragma unroll
    for (int e = 0; e < 4; ++e) {
        int idx = e * 256 + tid;
        int kk = idx >> 5, nn = idx & 31;
        ls[kk][nn] = Wp[(size_t)(k0 + kk) * N + n0 + nn];
    }
    __syncthreads();
#pragma unroll
    for (int e = 0; e < 2; ++e) {
        int idx = e * 256 + tid;
        int nn = idx >> 4, kp = (idx & 15) * 2;
        union { bf16_t h[2]; unsigned u; } pk;
        pk.h[0] = (bf16_t)ls[kp][nn];
        pk.h[1] = (bf16_t)ls[kp + 1][nn];
        *(unsigned*)&WTp[(size_t)(n0 + nn) * K + k0 + kp] = pk.u;
    }
}

// ---------------- barrier-free per-wave GEMMs, 3-buffer depth-2 pipeline ----------------
// 1 wave/block, 64x64 tile. Hazard-free schedule per iter k:
//   wait vmcnt<=8 (drain iter k's loads) -> sched_barrier -> ds_read(k) ->
//   glds(k+2) -> MFMA(k).
// glds(k+2) writes buf (k+2)%3 = (k-1)%3; it issues after all MFMA(k-1)
// (cross-sched_barrier, in-order issue), and MFMA issue implies ds_read(k-1)
// data already in VGPRs -> no LDS write/read race (r6 failure mode).
// Addresses are pointer-arith with constexpr k (r4-proven; offset arg stays 0).

__global__ __launch_bounds__(64) void gemm1_kernel(
    const bf16_t* __restrict__ xs, const bf16_t* __restrict__ w1t,
    const float* __restrict__ b1, const int* __restrict__ blk_p,
    bf16_t* __restrict__ h) {

    const int p = blk_p[blockIdx.x];
    if (p < 0) return;
    const int m0 = blockIdx.x * 64;
    const int n0 = blockIdx.y * 64;

    __shared__ __align__(16) bf16_t As[3][64 * 32];
    __shared__ __align__(16) bf16_t Bs[3][64 * 32];

    const int lane = threadIdx.x;
    const bf16_t* a_src[4];
    const bf16_t* b_src[4];
    int dstc[4];
#pragma unroll
    for (int i = 0; i < 4; ++i) {
        int c = i * 64 + lane;
        int r = c >> 2;
        int kl = (c & 3) ^ ((r >> 1) & 3);
        a_src[i] = xs + (size_t)(m0 + r) * K1 + kl * 8;
        b_src[i] = w1t + ((size_t)p * H_SZ + n0 + r) * K1 + kl * 8;
        dstc[i] = c * 8;
    }

    const int l16 = lane & 15, qd = lane >> 4;
    const int swz = (l16 >> 1) & 3;
    int aoff[4], boff[4];
#pragma unroll
    for (int i = 0; i < 4; ++i) aoff[i] = (i * 16 + l16) * 32 + ((qd ^ swz) * 8);
#pragma unroll
    for (int j = 0; j < 4; ++j) boff[j] = (j * 16 + l16) * 32 + ((qd ^ swz) * 8);

    f32x4 acc[4][4];
#pragma unroll
    for (int i = 0; i < 4; ++i)
#pragma unroll
        for (int j = 0; j < 4; ++j)
            acc[i][j] = (f32x4){0.f, 0.f, 0.f, 0.f};

    constexpr int NK = K1 / 32;   // 18
    // prologue: k=0 -> buf0, k=1 -> buf1 (16 outstanding)
#pragma unroll
    for (int i = 0; i < 4; ++i) glds16(a_src[i], &As[0][dstc[i]]);
#pragma unroll
    for (int i = 0; i < 4; ++i) glds16(b_src[i], &Bs[0][dstc[i]]);
#pragma unroll
    for (int i = 0; i < 4; ++i) glds16(a_src[i] + 32, &As[1][dstc[i]]);
#pragma unroll
    for (int i = 0; i < 4; ++i) glds16(b_src[i] + 32, &Bs[1][dstc[i]]);

    static_for<NK>([&](auto kc) {
        constexpr int k = kc.value;
        constexpr int cur = k % 3;
        if constexpr (k == NK - 1) __builtin_amdgcn_s_waitcnt(WAIT_VM0);
        else                       __builtin_amdgcn_s_waitcnt(WAIT_VM8);
        __builtin_amdgcn_sched_barrier(0);
        bf16x8 af[4], bfv[4];
#pragma unroll
        for (int i = 0; i < 4; ++i) af[i] = *(const bf16x8*)(&As[cur][aoff[i]]);
#pragma unroll
        for (int j = 0; j < 4; ++j) bfv[j] = *(const bf16x8*)(&Bs[cur][boff[j]]);
        if constexpr (k + 2 < NK) {
            constexpr int nxt = (k + 2) % 3;
#pragma unroll
            for (int i = 0; i < 4; ++i) glds16(a_src[i] + (k + 2) * 32, &As[nxt][dstc[i]]);
#pragma unroll
            for (int i = 0; i < 4; ++i) glds16(b_src[i] + (k + 2) * 32, &Bs[nxt][dstc[i]]);
        }
#pragma unroll
        for (int i = 0; i < 4; ++i)
#pragma unroll
            for (int j = 0; j < 4; ++j)
                acc[i][j] = __builtin_amdgcn_mfma_f32_16x16x32_bf16(af[i], bfv[j], acc[i][j], 0, 0, 0);
    });

    // epilogue: bias + relu -> h (padded sorted layout)
#pragma unroll
    for (int i = 0; i < 4; ++i) {
#pragma unroll
        for (int r = 0; r < 4; ++r) {
            int ml = i * 16 + qd * 4 + r;      // C/D: row = quad*4 + reg
            size_t row = (size_t)(m0 + ml);
#pragma unroll
            for (int j = 0; j < 4; ++j) {
                int n = n0 + j * 16 + l16;     // C/D: col = lane&15
                float v = acc[i][j][r] + b1[p * H_SZ + n];
                h[row * H_SZ + n] = (bf16_t)fmaxf(v, 0.f);
            }
        }
    }
}

__global__ __launch_bounds__(64) void gemm2_kernel(
    const bf16_t* __restrict__ h, const bf16_t* __restrict__ w2t,
    const float* __restrict__ b2, const int* __restrict__ blk_p,
    const int* __restrict__ rowidx, float* __restrict__ out) {

    const int p = blk_p[blockIdx.x];
    if (p < 0) return;
    const int m0 = blockIdx.x * 64;
    const int n0 = blockIdx.y * 64;

    __shared__ __align__(16) bf16_t As[3][64 * 32];
    __shared__ __align__(16) bf16_t Bs[3][64 * 32];

    const int lane = threadIdx.x;
    const bf16_t* a_src[4];
    const bf16_t* b_src[4];
    int dstc[4];
#pragma unroll
    for (int i = 0; i < 4; ++i) {
        int c = i * 64 + lane;
        int r = c >> 2;
        int kl = (c & 3) ^ ((r >> 1) & 3);
        a_src[i] = h + (size_t)(m0 + r) * H_SZ + kl * 8;
        b_src[i] = w2t + ((size_t)p * D_SZ + n0 + r) * H_SZ + kl * 8;
        dstc[i] = c * 8;
    }

    const int l16 = lane & 15, qd = lane >> 4;
    const int swz = (l16 >> 1) & 3;
    int aoff[4], boff[4];
#pragma unroll
    for (int i = 0; i < 4; ++i) aoff[i] = (i * 16 + l16) * 32 + ((qd ^ swz) * 8);
#pragma unroll
    for (int j = 0; j < 4; ++j) boff[j] = (j * 16 + l16) * 32 + ((qd ^ swz) * 8);

    f32x4 acc[4][4];
#pragma unroll
    for (int i = 0; i < 4; ++i)
#pragma unroll
        for (int j = 0; j < 4; ++j)
            acc[i][j] = (f32x4){0.f, 0.f, 0.f, 0.f};

    constexpr int NK = H_SZ / 32;   // 32
#pragma unroll
    for (int i = 0; i < 4; ++i) glds16(a_src[i], &As[0][dstc[i]]);
#pragma unroll
    for (int i = 0; i < 4; ++i) glds16(b_src[i], &Bs[0][dstc[i]]);
#pragma unroll
    for (int i = 0; i < 4; ++i) glds16(a_src[i] + 32, &As[1][dstc[i]]);
#pragma unroll
    for (int i = 0; i < 4; ++i) glds16(b_src[i] + 32, &Bs[1][dstc[i]]);

    static_for<NK>([&](auto kc) {
        constexpr int k = kc.value;
        constexpr int cur = k % 3;
        if constexpr (k == NK - 1) __builtin_amdgcn_s_waitcnt(WAIT_VM0);
        else                       __builtin_amdgcn_s_waitcnt(WAIT_VM8);
        __builtin_amdgcn_sched_barrier(0);
        bf16x8 af[4], bfv[4];
#pragma unroll
        for (int i = 0; i < 4; ++i) af[i] = *(const bf16x8*)(&As[cur][aoff[i]]);
#pragma unroll
        for (int j = 0; j < 4; ++j) bfv[j] = *(const bf16x8*)(&Bs[cur][boff[j]]);
        if constexpr (k + 2 < NK) {
            constexpr int nxt = (k + 2) % 3;
#pragma unroll
            for (int i = 0; i < 4; ++i) glds16(a_src[i] + (k + 2) * 32, &As[nxt][dstc[i]]);
#pragma unroll
            for (int i = 0; i < 4; ++i) glds16(b_src[i] + (k + 2) * 32, &Bs[nxt][dstc[i]]);
        }
#pragma unroll
        for (int i = 0; i < 4; ++i)
#pragma unroll
            for (int j = 0; j < 4; ++j)
                acc[i][j] = __builtin_amdgcn_mfma_f32_16x16x32_bf16(af[i], bfv[j], acc[i][j], 0, 0, 0);
    });

    // epilogue: bias, scatter to original rows; pad rows masked
#pragma unroll
    for (int i = 0; i < 4; ++i) {
#pragma unroll
        for (int r = 0; r < 4; ++r) {
            int ml = i * 16 + qd * 4 + r;
            int g = rowidx[m0 + ml];
            if (g >= 0) {
                size_t orow = (size_t)g * D_SZ;
#pragma unroll
                for (int j = 0; j < 4; ++j) {
                    int n = n0 + j * 16 + l16;
                    out[orow + n] = acc[i][j][r] + b2[p * D_SZ + n];
                }
            }
        }
    }
}

// ---------------- launch ----------------

extern "C" void kernel_launch(void* const* d_in, const int* in_sizes, int n_in,
                              void* d_out, int out_size, void* d_ws, size_t ws_size,
                              hipStream_t stream) {
    const float* latents = (const float*)d_in[0];
    const float* actions = (const float*)d_in[1];
    const int*   pol     = (const int*)d_in[2];
    const float* W1      = (const float*)d_in[3];
    const float* b1      = (const float*)d_in[4];
    const float* W2      = (const float*)d_in[5];
    const float* b2      = (const float*)d_in[6];
    float* out = (float*)d_out;

    char* ws = (char*)d_ws;
    int* counts    = (int*)ws;
    int* cursors   = counts + P_SZ;
    int* blk_p     = cursors + P_SZ;
    int* blockhist = blk_p + MB_MAX;
    int* rowidx    = blockhist + NSEG * P_SZ;
    size_t pos = ((size_t)(2 * P_SZ + MB_MAX + NSEG * P_SZ + BPAD) * sizeof(int) + 255) & ~(size_t)255;
    bf16_t* xs  = (bf16_t*)(ws + pos);  pos += (size_t)BPAD * K1 * 2;
    bf16_t* hbuf= (bf16_t*)(ws + pos);  pos += (size_t)BPAD * H_SZ * 2;
    bf16_t* w1t = (bf16_t*)(ws + pos);  pos += (size_t)P_SZ * H_SZ * K1 * 2;
    bf16_t* w2t = (bf16_t*)(ws + pos);  pos += (size_t)P_SZ * D_SZ * H_SZ * 2;

    hist_block<<<NSEG, 256, 0, stream>>>(pol, blockhist, rowidx);
    prefix_kernel<<<1, 64, 0, stream>>>(blockhist, counts, cursors, blk_p);
    scatter_agg<<<NSEG, 256, 0, stream>>>(pol, cursors, rowidx);
    prep_all<<<PREP_BLOCKS + TRANS_BLOCKS, 256, 0, stream>>>(
        latents, actions, rowidx, W1, W2, xs, w1t, w2t);
    gemm1_kernel<<<dim3(MB_MAX, H_SZ / 64), 64, 0, stream>>>(xs, w1t, b1, blk_p, hbuf);
    gemm2_kernel<<<dim3(MB_MAX, D_SZ / 64), 64, 0, stream>>>(hbuf, w2t, b2, blk_p, rowidx, out);
}

// Round 8
// 210.466 us; speedup vs baseline: 1.1311x; 1.1311x over previous
//
#include <hip/hip_runtime.h>
#include <hip/hip_bf16.h>
#include <stdint.h>

#define B_SZ 16384
#define P_SZ 8
#define D_SZ 512
#define A_SZ 64
#define K1 576    // D + A
#define H_SZ 1024
#define NSEG 64
#define MB_MAX 72               // max 256-row m-blocks after per-policy padding
#define BPAD (B_SZ + P_SZ*256)  // 18432 padded sorted-row capacity
#define PREP_BLOCKS (BPAD * 72 / 256)   // 5184
#define TRANS_BLOCKS (32 * 32 * 16)     // 16384

typedef __bf16 bf16_t;
typedef __bf16 bf16x8 __attribute__((ext_vector_type(8)));
typedef float f32x4 __attribute__((ext_vector_type(4)));

__device__ __forceinline__ void glds16(const void* g, void* l) {
    __builtin_amdgcn_global_load_lds(
        (const __attribute__((address_space(1))) unsigned*)g,
        (__attribute__((address_space(3))) unsigned*)l, 16, 0, 0);
}

// ---------------- sort prep ----------------

__global__ __launch_bounds__(256) void hist_block(const int* __restrict__ pol,
                                                  int* __restrict__ blockhist,
                                                  int* __restrict__ rowidx) {
    __shared__ int lc[P_SZ];
    int t = threadIdx.x;
    if (t < P_SZ) lc[t] = 0;
    __syncthreads();
    int gid = blockIdx.x * 256 + t;
    rowidx[gid] = -1;
    if (gid < BPAD - B_SZ) rowidx[B_SZ + gid] = -1;
    atomicAdd(&lc[pol[gid]], 1);
    __syncthreads();
    if (t < P_SZ) blockhist[blockIdx.x * P_SZ + t] = lc[t];
}

__global__ __launch_bounds__(64) void prefix_kernel(const int* __restrict__ blockhist,
                                                    int* __restrict__ counts,
                                                    int* __restrict__ cursors,
                                                    int* __restrict__ blk_p) {
    int t = threadIdx.x;
    if (t < P_SZ) {
        int s = 0;
        for (int b = 0; b < NSEG; ++b) s += blockhist[b * P_SZ + t];
        counts[t] = s;
    }
    __syncthreads();
    if (t == 0) {
        int run = 0;   // 256-aligned running offset
        for (int p = 0; p < P_SZ; ++p) {
            cursors[p] = run;
            int nb = (counts[p] + 255) >> 8;
            for (int b = 0; b < nb; ++b) blk_p[(run >> 8) + b] = p;
            run += nb * 256;
        }
        for (int b = run >> 8; b < MB_MAX; ++b) blk_p[b] = -1;
    }
}

__global__ __launch_bounds__(256) void scatter_agg(const int* __restrict__ pol,
                                                   int* __restrict__ cursors,
                                                   int* __restrict__ rowidx) {
    __shared__ int lc[P_SZ], base_s[P_SZ];
    int t = threadIdx.x;
    if (t < P_SZ) lc[t] = 0;
    __syncthreads();
    int i = blockIdx.x * 256 + t;
    int p = pol[i];
    int lpos = atomicAdd(&lc[p], 1);
    __syncthreads();
    if (t < P_SZ) base_s[t] = atomicAdd(&cursors[t], lc[t]);
    __syncthreads();
    rowidx[base_s[p] + lpos] = i;
}

// ---------------- prep_all: fused x-gather/convert + weight transposes ----------------

__global__ __launch_bounds__(256) void prep_all(const float* __restrict__ latents,
                                                const float* __restrict__ actions,
                                                const int* __restrict__ rowidx,
                                                const float* __restrict__ W1,
                                                const float* __restrict__ W2,
                                                bf16_t* __restrict__ xs,
                                                bf16_t* __restrict__ w1t,
                                                bf16_t* __restrict__ w2t) {
    int bx = blockIdx.x;
    int tid = threadIdx.x;
    if (bx < PREP_BLOCKS) {
        int idx = bx * 256 + tid;
        int s = idx / 72;
        int col = (idx - s * 72) * 8;
        int g = rowidx[s];
        bf16x8 o;
        if (g < 0) {
            o = (bf16x8){0,0,0,0,0,0,0,0};
        } else {
            const float* src;
            if (col < D_SZ) src = latents + (size_t)g * D_SZ + col;
            else            src = actions + (size_t)g * A_SZ + (col - D_SZ);
            f32x4 v0 = *(const f32x4*)src;
            f32x4 v1 = *(const f32x4*)(src + 4);
            o[0] = (bf16_t)v0[0]; o[1] = (bf16_t)v0[1]; o[2] = (bf16_t)v0[2]; o[3] = (bf16_t)v0[3];
            o[4] = (bf16_t)v1[0]; o[5] = (bf16_t)v1[1]; o[6] = (bf16_t)v1[2]; o[7] = (bf16_t)v1[3];
        }
        *(bf16x8*)(xs + (size_t)s * K1 + col) = o;
        return;
    }
    int tz = bx - PREP_BLOCKS;        // 0..16383
    int z = tz >> 10;                 // 0..15
    int rem = tz & 1023;
    int k0 = (rem & 31) * 32, n0 = (rem >> 5) * 32;
    int K = (z < P_SZ) ? K1 : H_SZ;
    int N = (z < P_SZ) ? H_SZ : D_SZ;
    if (k0 >= K || n0 >= N) return;
    int p = z & 7;
    const float* Wp = ((z < P_SZ) ? W1 : W2) + (size_t)p * K * N;
    bf16_t* WTp = ((z < P_SZ) ? w1t : w2t) + (size_t)p * N * K;
    __shared__ float ls[32][33];
#pragma unroll
    for (int e = 0; e < 4; ++e) {
        int idx = e * 256 + tid;
        int kk = idx >> 5, nn = idx & 31;
        ls[kk][nn] = Wp[(size_t)(k0 + kk) * N + n0 + nn];
    }
    __syncthreads();
#pragma unroll
    for (int e = 0; e < 2; ++e) {
        int idx = e * 256 + tid;
        int nn = idx >> 4, kp = (idx & 15) * 2;
        union { bf16_t h[2]; unsigned u; } pk;
        pk.h[0] = (bf16_t)ls[kp][nn];
        pk.h[1] = (bf16_t)ls[kp + 1][nn];
        *(unsigned*)&WTp[(size_t)(n0 + nn) * K + k0 + kp] = pk.u;
    }
}

// ---------------- GEMMs: BM=256, 4 waves (pure m-split), m97 2-barrier K-loop ----------
// Wave w computes rows [w*64, w*64+64) x all BN cols. Staging via glds16; XOR chunk
// swizzle (stored pos kc holds logical (kc)^((row>>1)&3)) -> 0 conflicts (measured).
// Per iter: gemm1 stages 24 KB for 256x128x32 MACs (0.023 B/MAC) -- r3's structure
// sustained 63 B/cy/CU staging; this needs 2.7x less per MAC.

__global__ __launch_bounds__(256, 2) void gemm1_kernel(
    const bf16_t* __restrict__ xs, const bf16_t* __restrict__ w1t,
    const float* __restrict__ b1, const int* __restrict__ blk_p,
    bf16_t* __restrict__ h) {

    const int p = blk_p[blockIdx.x];
    if (p < 0) return;
    const int m0 = blockIdx.x * 256;
    const int n0 = blockIdx.y * 128;

    __shared__ __align__(16) bf16_t As[256 * 32];   // 16 KB
    __shared__ __align__(16) bf16_t Bs[128 * 32];   // 8 KB

    const int tid = threadIdx.x;
    const int wave = tid >> 6, lane = tid & 63;

    // A: 1024 chunks, 16 glds slots; wave handles slots wave*4+i
    const bf16_t* a_src[4]; bf16_t* a_dst[4];
#pragma unroll
    for (int i = 0; i < 4; ++i) {
        int c = (wave * 4 + i) * 64 + lane;
        int r = c >> 2;
        int kl = (c & 3) ^ ((r >> 1) & 3);
        a_src[i] = xs + (size_t)(m0 + r) * K1 + kl * 8;
        a_dst[i] = As + c * 8;
    }
    // B: 512 chunks, 8 slots; wave handles slots wave*2+i
    const bf16_t* b_src[2]; bf16_t* b_dst[2];
#pragma unroll
    for (int i = 0; i < 2; ++i) {
        int c = (wave * 2 + i) * 64 + lane;
        int r = c >> 2;
        int kl = (c & 3) ^ ((r >> 1) & 3);
        b_src[i] = w1t + ((size_t)p * H_SZ + n0 + r) * K1 + kl * 8;
        b_dst[i] = Bs + c * 8;
    }

    const int l16 = lane & 15, qd = lane >> 4;
    const int swz = (l16 >> 1) & 3;
    int aoff[4], boff[8];
#pragma unroll
    for (int i = 0; i < 4; ++i) aoff[i] = (wave * 64 + i * 16 + l16) * 32 + ((qd ^ swz) * 8);
#pragma unroll
    for (int j = 0; j < 8; ++j) boff[j] = (j * 16 + l16) * 32 + ((qd ^ swz) * 8);

    f32x4 acc[4][8];
#pragma unroll
    for (int i = 0; i < 4; ++i)
#pragma unroll
        for (int j = 0; j < 8; ++j)
            acc[i][j] = (f32x4){0.f, 0.f, 0.f, 0.f};

    for (int kt = 0; kt < K1; kt += 32) {
        __syncthreads();   // previous iter's frags consumed
#pragma unroll
        for (int i = 0; i < 4; ++i) glds16(a_src[i] + kt, a_dst[i]);
#pragma unroll
        for (int i = 0; i < 2; ++i) glds16(b_src[i] + kt, b_dst[i]);
        __syncthreads();   // staging complete (compiler inserts vmcnt(0))
        bf16x8 af[4], bfv[8];
#pragma unroll
        for (int i = 0; i < 4; ++i) af[i] = *(const bf16x8*)(As + aoff[i]);
#pragma unroll
        for (int j = 0; j < 8; ++j) bfv[j] = *(const bf16x8*)(Bs + boff[j]);
#pragma unroll
        for (int i = 0; i < 4; ++i)
#pragma unroll
            for (int j = 0; j < 8; ++j)
                acc[i][j] = __builtin_amdgcn_mfma_f32_16x16x32_bf16(af[i], bfv[j], acc[i][j], 0, 0, 0);
    }

    // epilogue: bias + relu -> h (padded sorted layout)
#pragma unroll
    for (int i = 0; i < 4; ++i) {
#pragma unroll
        for (int r = 0; r < 4; ++r) {
            int ml = wave * 64 + i * 16 + qd * 4 + r;   // C/D: row = quad*4 + reg
            size_t row = (size_t)(m0 + ml);
#pragma unroll
            for (int j = 0; j < 8; ++j) {
                int n = n0 + j * 16 + l16;              // C/D: col = lane&15
                float v = acc[i][j][r] + b1[p * H_SZ + n];
                h[row * H_SZ + n] = (bf16_t)fmaxf(v, 0.f);
            }
        }
    }
}

__global__ __launch_bounds__(256, 2) void gemm2_kernel(
    const bf16_t* __restrict__ h, const bf16_t* __restrict__ w2t,
    const float* __restrict__ b2, const int* __restrict__ blk_p,
    const int* __restrict__ rowidx, float* __restrict__ out) {

    const int p = blk_p[blockIdx.x];
    if (p < 0) return;
    const int m0 = blockIdx.x * 256;
    const int n0 = blockIdx.y * 64;

    __shared__ __align__(16) bf16_t As[256 * 32];   // 16 KB
    __shared__ __align__(16) bf16_t Bs[64 * 32];    // 4 KB

    const int tid = threadIdx.x;
    const int wave = tid >> 6, lane = tid & 63;

    const bf16_t* a_src[4]; bf16_t* a_dst[4];
#pragma unroll
    for (int i = 0; i < 4; ++i) {
        int c = (wave * 4 + i) * 64 + lane;
        int r = c >> 2;
        int kl = (c & 3) ^ ((r >> 1) & 3);
        a_src[i] = h + (size_t)(m0 + r) * H_SZ + kl * 8;
        a_dst[i] = As + c * 8;
    }
    // B: 256 chunks, 4 slots; wave handles slot `wave`
    const bf16_t* b_src0; bf16_t* b_dst0;
    {
        int c = wave * 64 + lane;
        int r = c >> 2;
        int kl = (c & 3) ^ ((r >> 1) & 3);
        b_src0 = w2t + ((size_t)p * D_SZ + n0 + r) * H_SZ + kl * 8;
        b_dst0 = Bs + c * 8;
    }

    const int l16 = lane & 15, qd = lane >> 4;
    const int swz = (l16 >> 1) & 3;
    int aoff[4], boff[4];
#pragma unroll
    for (int i = 0; i < 4; ++i) aoff[i] = (wave * 64 + i * 16 + l16) * 32 + ((qd ^ swz) * 8);
#pragma unroll
    for (int j = 0; j < 4; ++j) boff[j] = (j * 16 + l16) * 32 + ((qd ^ swz) * 8);

    f32x4 acc[4][4];
#pragma unroll
    for (int i = 0; i < 4; ++i)
#pragma unroll
        for (int j = 0; j < 4; ++j)
            acc[i][j] = (f32x4){0.f, 0.f, 0.f, 0.f};

    for (int kt = 0; kt < H_SZ; kt += 32) {
        __syncthreads();
#pragma unroll
        for (int i = 0; i < 4; ++i) glds16(a_src[i] + kt, a_dst[i]);
        glds16(b_src0 + kt, b_dst0);
        __syncthreads();
        bf16x8 af[4], bfv[4];
#pragma unroll
        for (int i = 0; i < 4; ++i) af[i] = *(const bf16x8*)(As + aoff[i]);
#pragma unroll
        for (int j = 0; j < 4; ++j) bfv[j] = *(const bf16x8*)(Bs + boff[j]);
#pragma unroll
        for (int i = 0; i < 4; ++i)
#pragma unroll
            for (int j = 0; j < 4; ++j)
                acc[i][j] = __builtin_amdgcn_mfma_f32_16x16x32_bf16(af[i], bfv[j], acc[i][j], 0, 0, 0);
    }

    // epilogue: bias, scatter to original rows; pad rows masked
#pragma unroll
    for (int i = 0; i < 4; ++i) {
#pragma unroll
        for (int r = 0; r < 4; ++r) {
            int ml = wave * 64 + i * 16 + qd * 4 + r;
            int g = rowidx[m0 + ml];
            if (g >= 0) {
                size_t orow = (size_t)g * D_SZ;
#pragma unroll
                for (int j = 0; j < 4; ++j) {
                    int n = n0 + j * 16 + l16;
                    out[orow + n] = acc[i][j][r] + b2[p * D_SZ + n];
                }
            }
        }
    }
}

// ---------------- launch ----------------

extern "C" void kernel_launch(void* const* d_in, const int* in_sizes, int n_in,
                              void* d_out, int out_size, void* d_ws, size_t ws_size,
                              hipStream_t stream) {
    const float* latents = (const float*)d_in[0];
    const float* actions = (const float*)d_in[1];
    const int*   pol     = (const int*)d_in[2];
    const float* W1      = (const float*)d_in[3];
    const float* b1      = (const float*)d_in[4];
    const float* W2      = (const float*)d_in[5];
    const float* b2      = (const float*)d_in[6];
    float* out = (float*)d_out;

    char* ws = (char*)d_ws;
    int* counts    = (int*)ws;
    int* cursors   = counts + P_SZ;
    int* blk_p     = cursors + P_SZ;
    int* blockhist = blk_p + MB_MAX;
    int* rowidx    = blockhist + NSEG * P_SZ;
    size_t pos = ((size_t)(2 * P_SZ + MB_MAX + NSEG * P_SZ + BPAD) * sizeof(int) + 255) & ~(size_t)255;
    bf16_t* xs  = (bf16_t*)(ws + pos);  pos += (size_t)BPAD * K1 * 2;
    bf16_t* hbuf= (bf16_t*)(ws + pos);  pos += (size_t)BPAD * H_SZ * 2;
    bf16_t* w1t = (bf16_t*)(ws + pos);  pos += (size_t)P_SZ * H_SZ * K1 * 2;
    bf16_t* w2t = (bf16_t*)(ws + pos);  pos += (size_t)P_SZ * D_SZ * H_SZ * 2;

    hist_block<<<NSEG, 256, 0, stream>>>(pol, blockhist, rowidx);
    prefix_kernel<<<1, 64, 0, stream>>>(blockhist, counts, cursors, blk_p);
    scatter_agg<<<NSEG, 256, 0, stream>>>(pol, cursors, rowidx);
    prep_all<<<PREP_BLOCKS + TRANS_BLOCKS, 256, 0, stream>>>(
        latents, actions, rowidx, W1, W2, xs, w1t, w2t);
    gemm1_kernel<<<dim3(MB_MAX, H_SZ / 128), 256, 0, stream>>>(xs, w1t, b1, blk_p, hbuf);
    gemm2_kernel<<<dim3(MB_MAX, D_SZ / 64), 256, 0, stream>>>(hbuf, w2t, b2, blk_p, rowidx, out);
}